// Round 1
// baseline (70.391 us; speedup 1.0000x reference)
//
#include <hip/hip_runtime.h>

// Problem constants (from reference)
constexpr int NPTS  = 1024;   // points per batch in pointcloud
constexpr int NT    = 21;     // targets per batch
constexpr int KSEL  = 64;     // top-k
constexpr int BLOCK = 256;

__device__ __forceinline__ unsigned key_of(float d) {
    // monotone float->uint transform (total order matching float <)
    unsigned u = __float_as_uint(d);
    return (u & 0x80000000u) ? ~u : (u | 0x80000000u);
}

__global__ __launch_bounds__(BLOCK) void knn_mask_kernel(
    const float* __restrict__ pc,   // (512, 1024, 3)
    const float* __restrict__ tgt,  // (512, 21, 3)
    float* __restrict__ out)        // (512, 21, 1024, 3)
{
    const int bt  = blockIdx.x;        // 0 .. 512*21-1
    const int b   = bt / NT;
    const int tq  = bt % NT;
    const int tid = threadIdx.x;

    __shared__ float         s_pc[NPTS * 3];   // 12 KB
    __shared__ unsigned      s_key[NPTS];      // 4 KB
    __shared__ unsigned      s_hist[256];      // 1 KB
    __shared__ unsigned      s_scan[BLOCK];    // 1 KB
    __shared__ unsigned char s_sel[NPTS];      // 1 KB
    __shared__ unsigned      s_prefix, s_want;

    // ---- stage pc[b] into LDS (768 x float4, coalesced) ----
    const float4* pc4   = reinterpret_cast<const float4*>(pc + (size_t)b * (NPTS * 3));
    float4*       s_pc4 = reinterpret_cast<float4*>(s_pc);
    for (int i = tid; i < NPTS * 3 / 4; i += BLOCK) s_pc4[i] = pc4[i];

    // target point (broadcast read; L1/L2 cached)
    const float* tp = tgt + ((size_t)b * NT + tq) * 3;
    const float  t0 = tp[0], t1 = tp[1], t2 = tp[2];
    const float  dt = t0 * t0 + t1 * t1 + t2 * t2;

    __syncthreads();

    // ---- distance keys (same fp32 formula as reference) ----
    for (int n = tid; n < NPTS; n += BLOCK) {
        const float p0 = s_pc[3 * n + 0];
        const float p1 = s_pc[3 * n + 1];
        const float p2 = s_pc[3 * n + 2];
        const float d  = dt + (p0 * p0 + p1 * p1 + p2 * p2)
                            - 2.0f * (t0 * p0 + t1 * p1 + t2 * p2);
        s_key[n] = key_of(d);
    }
    __syncthreads();

    // ---- exact radix-select of the KSEL-th smallest key (MSB-first, 8-bit digits) ----
    unsigned prefix = 0;     // high bits fixed so far
    unsigned want   = KSEL;  // how many still to take within the candidate class
    for (int shift = 24; shift >= 0; shift -= 8) {
        if (tid < 256) s_hist[tid] = 0;
        __syncthreads();
        for (int n = tid; n < NPTS; n += BLOCK) {
            const unsigned k = s_key[n];
            if ((shift == 24) || ((k >> (shift + 8)) == prefix)) {
                atomicAdd(&s_hist[(k >> shift) & 0xFFu], 1u);
            }
        }
        __syncthreads();
        // wave 0: find the bucket where the cumulative count crosses `want`
        if (tid < 64) {
            const unsigned c0 = s_hist[4 * tid + 0];
            const unsigned c1 = s_hist[4 * tid + 1];
            const unsigned c2 = s_hist[4 * tid + 2];
            const unsigned c3 = s_hist[4 * tid + 3];
            const unsigned lane_sum = c0 + c1 + c2 + c3;
            // inclusive shfl scan over 64 lanes
            unsigned incl = lane_sum;
            #pragma unroll
            for (int off = 1; off < 64; off <<= 1) {
                const unsigned v = __shfl_up(incl, off, 64);
                if (tid >= off) incl += v;
            }
            unsigned run = incl - lane_sum;  // exclusive prefix before my 4 buckets
            const unsigned cs[4] = {c0, c1, c2, c3};
            #pragma unroll
            for (int j = 0; j < 4; ++j) {
                if (run < want && want <= run + cs[j]) {
                    s_prefix = (prefix << 8) | (unsigned)(4 * tid + j);
                    s_want   = want - run;
                }
                run += cs[j];
            }
        }
        __syncthreads();
        prefix = s_prefix;
        want   = s_want;
        __syncthreads();
    }
    const unsigned kth = prefix;  // exact key value at sorted position KSEL-1

    // ---- stable tie ranking (lower index first, matching jax.lax.top_k) ----
    // each thread owns 4 consecutive n
    unsigned cnt = 0;
    {
        const int n0 = tid * 4;
        #pragma unroll
        for (int j = 0; j < 4; ++j) cnt += (s_key[n0 + j] == kth) ? 1u : 0u;
    }
    s_scan[tid] = cnt;
    __syncthreads();
    // Hillis-Steele inclusive scan over 256 thread counts
    for (int off = 1; off < BLOCK; off <<= 1) {
        const unsigned v = (tid >= off) ? s_scan[tid - off] : 0u;
        __syncthreads();
        s_scan[tid] += v;
        __syncthreads();
    }
    unsigned run = s_scan[tid] - cnt;  // exclusive rank of my first equal element
    {
        const int n0 = tid * 4;
        #pragma unroll
        for (int j = 0; j < 4; ++j) {
            const unsigned k = s_key[n0 + j];
            unsigned char sel;
            if (k < kth)       sel = 1;
            else if (k == kth) { sel = (run < want) ? 1 : 0; ++run; }
            else               sel = 0;
            s_sel[n0 + j] = sel;
        }
    }
    __syncthreads();

    // ---- coalesced float4 output write: out[b,t,n,:] = sel ? pc[b,n,:] : 0 ----
    float4* out4 = reinterpret_cast<float4*>(out + (size_t)bt * (NPTS * 3));
    for (int i = tid; i < NPTS * 3 / 4; i += BLOCK) {
        const int e = 4 * i;
        float4 v;
        v.x = s_sel[(e + 0) / 3] ? s_pc[e + 0] : 0.0f;
        v.y = s_sel[(e + 1) / 3] ? s_pc[e + 1] : 0.0f;
        v.z = s_sel[(e + 2) / 3] ? s_pc[e + 2] : 0.0f;
        v.w = s_sel[(e + 3) / 3] ? s_pc[e + 3] : 0.0f;
        out4[i] = v;
    }
}

extern "C" void kernel_launch(void* const* d_in, const int* in_sizes, int n_in,
                              void* d_out, int out_size, void* d_ws, size_t ws_size,
                              hipStream_t stream) {
    const float* pc  = (const float*)d_in[0];  // (512,1024,3)
    const float* tgt = (const float*)d_in[1];  // (512,21,3)
    float*       out = (float*)d_out;          // (512,21,1024,3)

    const int B = in_sizes[0] / (NPTS * 3);    // 512
    const int nblocks = B * NT;                // 10752

    knn_mask_kernel<<<nblocks, BLOCK, 0, stream>>>(pc, tgt, out);
}

// Round 2
// 56.977 us; speedup vs baseline: 1.2354x; 1.2354x over previous
//
#include <hip/hip_runtime.h>

constexpr int NPTS  = 1024;   // points per batch
constexpr int NT    = 21;     // targets per batch
constexpr int KSEL  = 64;     // top-k
constexpr int BLOCK = 256;    // 4 waves, 1 wave per (b,t)
constexpr int PPL   = 16;     // points per lane (1024 / 64)

__device__ __forceinline__ unsigned key_of(float d) {
    // monotone float->uint transform (total order matching float <)
    unsigned u = __float_as_uint(d);
    return (u & 0x80000000u) ? ~u : (u | 0x80000000u);
}

__device__ __forceinline__ unsigned mbcnt64(unsigned long long m) {
    // popcount of m over lanes strictly below this lane
    unsigned lo = __builtin_amdgcn_mbcnt_lo((unsigned)m, 0u);
    return __builtin_amdgcn_mbcnt_hi((unsigned)(m >> 32), lo);
}

__global__ __launch_bounds__(BLOCK) void knn_mask_wave_kernel(
    const float* __restrict__ pc,   // (B, 1024, 3)
    const float* __restrict__ tgt,  // (B, 21, 3)
    float* __restrict__ out,        // (B, 21, 1024, 3)
    int total_bt)
{
    const int wave = threadIdx.x >> 6;
    const int lane = threadIdx.x & 63;
    const int bt   = blockIdx.x * 4 + wave;
    if (bt >= total_bt) return;          // wave-uniform
    const int b  = bt / NT;
    const int tq = bt % NT;

    // ---- load 16 consecutive points (48 floats = 12 float4) into registers ----
    float f[PPL * 3];
    {
        const float4* src = reinterpret_cast<const float4*>(pc + (size_t)b * (NPTS * 3))
                          + (size_t)lane * 12;
        #pragma unroll
        for (int j = 0; j < 12; ++j) {
            const float4 v = src[j];
            f[4 * j + 0] = v.x; f[4 * j + 1] = v.y;
            f[4 * j + 2] = v.z; f[4 * j + 3] = v.w;
        }
    }

    // target point (wave-uniform)
    const float* tp = tgt + ((size_t)b * NT + tq) * 3;
    const float  t0 = tp[0], t1 = tp[1], t2 = tp[2];
    const float  dt = t0 * t0 + t1 * t1 + t2 * t2;

    // ---- distance keys (same fp32 expression as the passing round-1 kernel) ----
    unsigned key[PPL];
    #pragma unroll
    for (int i = 0; i < PPL; ++i) {
        const float p0 = f[3 * i + 0];
        const float p1 = f[3 * i + 1];
        const float p2 = f[3 * i + 2];
        const float d  = dt + (p0 * p0 + p1 * p1 + p2 * p2)
                            - 2.0f * (t0 * p0 + t1 * p1 + t2 * p2);
        key[i] = key_of(d);
    }

    // ---- barrier-free bitwise binary search for the KSEL-th smallest key ----
    // invariant: keys with (key >> s) <  p are selected,
    //            keys with (key >> s) == p are candidates (cls of them, want slots left)
    unsigned p = 0, want = KSEL, cls = NPTS;
    int s = 32;
    bool early = false;
    while (s > 0) {
        --s;
        const unsigned p2 = p << 1;      // candidate prefix with next bit = 0
        unsigned cnt = 0;
        #pragma unroll
        for (int i = 0; i < PPL; ++i) cnt += ((key[i] >> s) == p2) ? 1u : 0u;
        // wave-total of cnt (0..16) via 5 ballots -> scalar popcounts
        unsigned total = 0;
        #pragma unroll
        for (int j = 0; j < 5; ++j)
            total += (unsigned)__popcll(__ballot((cnt >> j) & 1u)) << j;
        if (want <= total) { p = p2;      cls  = total; }
        else               { want -= total; p = p2 | 1u; cls -= total; }
        if (cls == want) { early = true; break; }   // all candidates selected
    }

    // ---- selection flags (exact, stable lowest-index tie-break) ----
    unsigned selmask = 0;   // bit i => point (16*lane + i) selected
    if (early) {
        #pragma unroll
        for (int i = 0; i < PPL; ++i)
            if ((key[i] >> s) <= p) selmask |= (1u << i);
    } else {
        const unsigned kth = p;          // exact key at sorted position KSEL-1
        unsigned cnt_eq = 0;
        #pragma unroll
        for (int i = 0; i < PPL; ++i) cnt_eq += (key[i] == kth) ? 1u : 0u;
        // exclusive cross-lane prefix of cnt_eq via mbcnt of 5 ballots
        unsigned run = 0;
        #pragma unroll
        for (int j = 0; j < 5; ++j)
            run += mbcnt64(__ballot((cnt_eq >> j) & 1u)) << j;
        #pragma unroll
        for (int i = 0; i < PPL; ++i) {
            const bool eq = (key[i] == kth);
            if (key[i] < kth || (eq && run < want)) selmask |= (1u << i);
            run += eq ? 1u : 0u;
        }
    }

    // ---- write out[bt, 16*lane .. 16*lane+15, :] = sel ? pc : 0  (12 float4/lane) ----
    float4* dst = reinterpret_cast<float4*>(out + (size_t)bt * (NPTS * 3))
                + (size_t)lane * 12;
    #pragma unroll
    for (int j = 0; j < 12; ++j) {
        float4 v;
        v.x = (selmask >> ((4 * j + 0) / 3)) & 1u ? f[4 * j + 0] : 0.0f;
        v.y = (selmask >> ((4 * j + 1) / 3)) & 1u ? f[4 * j + 1] : 0.0f;
        v.z = (selmask >> ((4 * j + 2) / 3)) & 1u ? f[4 * j + 2] : 0.0f;
        v.w = (selmask >> ((4 * j + 3) / 3)) & 1u ? f[4 * j + 3] : 0.0f;
        dst[j] = v;
    }
}

extern "C" void kernel_launch(void* const* d_in, const int* in_sizes, int n_in,
                              void* d_out, int out_size, void* d_ws, size_t ws_size,
                              hipStream_t stream) {
    const float* pc  = (const float*)d_in[0];  // (B,1024,3)
    const float* tgt = (const float*)d_in[1];  // (B,21,3)
    float*       out = (float*)d_out;          // (B,21,1024,3)

    const int B        = in_sizes[0] / (NPTS * 3);   // 512
    const int total_bt = B * NT;                      // 10752
    const int nblocks  = (total_bt + 3) / 4;          // 2688

    knn_mask_wave_kernel<<<nblocks, BLOCK, 0, stream>>>(pc, tgt, out, total_bt);
}

// Round 3
// 39.619 us; speedup vs baseline: 1.7767x; 1.4381x over previous
//
#include <hip/hip_runtime.h>

constexpr int NPTS  = 1024;   // points per batch
constexpr int NT    = 21;     // targets per batch
constexpr int KSEL  = 64;     // top-k
constexpr int BLOCK = 256;    // 4 waves, 1 wave per (b,t)
constexpr int PPL   = 16;     // points per lane (1024 / 64)

__device__ __forceinline__ unsigned key_of(float d) {
    // monotone float->uint transform (total order matching float <)
    unsigned u = __float_as_uint(d);
    return (u & 0x80000000u) ? ~u : (u | 0x80000000u);
}

__device__ __forceinline__ unsigned mbcnt64(unsigned long long m) {
    // popcount of m over lanes strictly below this lane
    unsigned lo = __builtin_amdgcn_mbcnt_lo((unsigned)m, 0u);
    return __builtin_amdgcn_mbcnt_hi((unsigned)(m >> 32), lo);
}

__global__ __launch_bounds__(BLOCK) void knn_mask_wave_kernel(
    const float* __restrict__ pc,   // (B, 1024, 3)
    const float* __restrict__ tgt,  // (B, 21, 3)
    float* __restrict__ out,        // (B, 21, 1024, 3)
    int total_bt)
{
    const int wave = threadIdx.x >> 6;
    const int lane = threadIdx.x & 63;
    const int bt   = blockIdx.x * 4 + wave;
    if (bt >= total_bt) return;          // wave-uniform
    const int b  = bt / NT;
    const int tq = bt % NT;

    const float4* src4 = reinterpret_cast<const float4*>(pc + (size_t)b * (NPTS * 3));

    // target point (wave-uniform)
    const float* tp = tgt + ((size_t)b * NT + tq) * 3;
    const float  t0 = tp[0], t1 = tp[1], t2 = tp[2];
    const float  dt = t0 * t0 + t1 * t1 + t2 * t2;

    // ---- phase 1: load my 16 consecutive points, compute keys ----
    // (scattered 16B loads over a 12 KB L1/L2-hot tile; values die after keys)
    unsigned key[PPL];
    {
        float f[PPL * 3];
        const float4* src = src4 + (size_t)lane * 12;
        #pragma unroll
        for (int j = 0; j < 12; ++j) {
            const float4 v = src[j];
            f[4 * j + 0] = v.x; f[4 * j + 1] = v.y;
            f[4 * j + 2] = v.z; f[4 * j + 3] = v.w;
        }
        #pragma unroll
        for (int i = 0; i < PPL; ++i) {
            const float p0 = f[3 * i + 0];
            const float p1 = f[3 * i + 1];
            const float p2 = f[3 * i + 2];
            const float d  = dt + (p0 * p0 + p1 * p1 + p2 * p2)
                                - 2.0f * (t0 * p0 + t1 * p1 + t2 * p2);
            key[i] = key_of(d);
        }
    }

    // ---- phase 2: barrier-free bitwise binary search for the KSEL-th smallest ----
    unsigned p = 0, want = KSEL, cls = NPTS;
    int s = 32;
    bool early = false;
    while (s > 0) {
        --s;
        const unsigned p2 = p << 1;      // candidate prefix with next bit = 0
        unsigned cnt = 0;
        #pragma unroll
        for (int i = 0; i < PPL; ++i) cnt += ((key[i] >> s) == p2) ? 1u : 0u;
        unsigned total = 0;
        #pragma unroll
        for (int j = 0; j < 5; ++j)
            total += (unsigned)__popcll(__ballot((cnt >> j) & 1u)) << j;
        if (want <= total) { p = p2;        cls  = total; }
        else               { want -= total; p = p2 | 1u;  cls -= total; }
        if (cls == want) { early = true; break; }   // whole candidate class selected
    }

    // ---- phase 3: selection flags for my 16 points (stable lowest-index ties) ----
    unsigned selmask = 0;   // bit i => point (16*lane + i) selected
    if (early) {
        #pragma unroll
        for (int i = 0; i < PPL; ++i)
            if ((key[i] >> s) <= p) selmask |= (1u << i);
    } else {
        const unsigned kth = p;          // exact key at sorted position KSEL-1
        unsigned cnt_eq = 0;
        #pragma unroll
        for (int i = 0; i < PPL; ++i) cnt_eq += (key[i] == kth) ? 1u : 0u;
        unsigned run = 0;
        #pragma unroll
        for (int j = 0; j < 5; ++j)
            run += mbcnt64(__ballot((cnt_eq >> j) & 1u)) << j;
        #pragma unroll
        for (int i = 0; i < PPL; ++i) {
            const bool eq = (key[i] == kth);
            if (key[i] < kth || (eq && run < want)) selmask |= (1u << i);
            run += eq ? 1u : 0u;
        }
    }

    // ---- phase 4: fully-coalesced store, output-major ownership ----
    // lane l stores float4 chunk m = 64j + l; values re-read coalesced (L1-hot),
    // selection bits fetched cross-lane via shfl (ds_bpermute). No LDS, no barriers.
    float4* dst4 = reinterpret_cast<float4*>(out + (size_t)bt * (NPTS * 3));
    #pragma unroll
    for (int j = 0; j < 12; ++j) {
        const int      m  = 64 * j + lane;
        const float4   g  = src4[m];
        const unsigned e0 = 4u * (unsigned)m;
        const unsigned q  = e0 / 3u;          // first point covered by this chunk
        const unsigned u  = e0 - 3u * q;      // 0..2: offset of chunk start in point q
        const unsigned sm0 = (unsigned)__shfl((int)selmask, (int)(q >> 4), 64);
        const unsigned sm1 = (unsigned)__shfl((int)selmask, (int)((q + 1u) >> 4), 64);
        const unsigned b0  = (sm0 >> (q & 15u)) & 1u;
        const unsigned b1  = (sm1 >> ((q + 1u) & 15u)) & 1u;
        float4 v;
        v.x = b0                     ? g.x : 0.0f;   // elem e0   -> always point q
        v.y = ((u == 2u) ? b1 : b0)  ? g.y : 0.0f;   // elem e0+1
        v.z = ((u == 0u) ? b0 : b1)  ? g.z : 0.0f;   // elem e0+2
        v.w = b1                     ? g.w : 0.0f;   // elem e0+3 -> always point q+1
        dst4[m] = v;
    }
}

extern "C" void kernel_launch(void* const* d_in, const int* in_sizes, int n_in,
                              void* d_out, int out_size, void* d_ws, size_t ws_size,
                              hipStream_t stream) {
    const float* pc  = (const float*)d_in[0];  // (B,1024,3)
    const float* tgt = (const float*)d_in[1];  // (B,21,3)
    float*       out = (float*)d_out;          // (B,21,1024,3)

    const int B        = in_sizes[0] / (NPTS * 3);   // 512
    const int total_bt = B * NT;                      // 10752
    const int nblocks  = (total_bt + 3) / 4;          // 2688

    knn_mask_wave_kernel<<<nblocks, BLOCK, 0, stream>>>(pc, tgt, out, total_bt);
}